// Round 4
// baseline (1062.836 us; speedup 1.0000x reference)
//
#include <hip/hip_runtime.h>
#include <stdint.h>

// Problem constants (DGCNN propagation). Inputs/outputs are FLOAT32 (per the
// reference's jnp.float32 setup_inputs); internals use bf16 MFMA (2% threshold).
#define B_   16
#define CIN  384     // C
#define GS   4096    // source points (power of 2 -> maskable)
#define GD   1024    // query points  (power of 2 -> maskable)
#define M1   512     // block1 out channels
#define K2C  512     // block2 in channels (= M1)
#define M2   384     // block2 out channels (= C)
#define NEG  0.2f
#define EPS_ 1e-5f

typedef __bf16 bf16x8 __attribute__((ext_vector_type(8)));
typedef float  f32x4  __attribute__((ext_vector_type(4)));

__device__ __forceinline__ float bf2f(ushort u) {
  uint32_t v = ((uint32_t)u) << 16;
  return __builtin_bit_cast(float, v);
}
__device__ __forceinline__ ushort f2bf(float f) {
  uint32_t x = __builtin_bit_cast(uint32_t, f);
  x += 0x7FFFu + ((x >> 16) & 1u);
  return (ushort)(x >> 16);
}

// ---------------- transpose+convert [b][C][N] f32 -> [b][N][C] bf16 ----------------
__global__ void k_transpose(const float* __restrict__ src, ushort* __restrict__ dst,
                            int Cdim, int N) {
  __shared__ ushort tile[32][33];
  int b = blockIdx.z;
  int n0 = blockIdx.x * 32, c0 = blockIdx.y * 32;
  const float* s = src + (size_t)b * Cdim * N;
  ushort* d = dst + (size_t)b * Cdim * N;
  int tx = threadIdx.x, ty = threadIdx.y;
#pragma unroll
  for (int i = 0; i < 4; i++) {
    int c = c0 + ty + i * 8;
    tile[ty + i * 8][tx] = f2bf(s[(size_t)c * N + n0 + tx]);
  }
  __syncthreads();
#pragma unroll
  for (int i = 0; i < 4; i++) {
    int n = n0 + ty + i * 8;
    d[(size_t)n * Cdim + c0 + tx] = tile[tx][ty + i * 8];
  }
}

// ---------------- weight prep: Wa = bf16(W[:, :Kh]), Wd = bf16(W[:, Kh:] - W[:, :Kh]) ----------------
__global__ void k_wprep(const float* __restrict__ W, ushort* __restrict__ Wa,
                        ushort* __restrict__ Wd, int Khalf) {
  int t = blockIdx.x * 256 + threadIdx.x;
  int o = t / Khalf, c = t % Khalf;
  float wa = W[(size_t)o * 2 * Khalf + c];
  float wb = W[(size_t)o * 2 * Khalf + Khalf + c];
  Wa[t] = f2bf(wa);
  Wd[t] = f2bf(wb - wa);
}

// ---------------- kNN (top-4 smallest dist, ascending-index tie-break) ----------------
// fp32 coords, exact reference op order; chunked LDS staging (16 KB).
template<int GSRC>
__global__ void k_knn(const float* __restrict__ cq, const float* __restrict__ ck,
                      int* __restrict__ idx) {
#pragma clang fp contract(off)
  const int CH = 1024;
  __shared__ float sx[CH], sy[CH], sz[CH], s2[CH];
  int b = blockIdx.y;
  const float* ckb = ck + (size_t)b * 3 * GSRC;
  int q = blockIdx.x * 256 + threadIdx.x;
  const float* cqb = cq + (size_t)b * 3 * GD;
  float qx = cqb[q], qy = cqb[GD + q], qz = cqb[2 * GD + q];
  float q2 = (qx * qx + qy * qy) + qz * qz;   // matches ref op order
  float d0 = 1e30f, d1 = 1e30f, d2 = 1e30f, d3 = 1e30f;
  int i0 = 0, i1 = 0, i2 = 0, i3 = 0;
  for (int c0 = 0; c0 < GSRC; c0 += CH) {
    __syncthreads();
    for (int i = threadIdx.x; i < CH; i += 256) {
      float x = ckb[c0 + i];
      float y = ckb[GSRC + c0 + i];
      float z = ckb[2 * GSRC + c0 + i];
      sx[i] = x; sy[i] = y; sz[i] = z;
      s2[i] = (x * x + y * y) + z * z;
    }
    __syncthreads();
    for (int jj = 0; jj < CH; jj++) {
      float dot = (qx * sx[jj] + qy * sy[jj]) + qz * sz[jj];
      float d = (q2 + s2[jj]) - 2.0f * dot;
      int j = c0 + jj;
      if (d < d3) {
        if (d < d2) {
          d3 = d2; i3 = i2;
          if (d < d1) {
            d2 = d1; i2 = i1;
            if (d < d0) { d1 = d0; i1 = i0; d0 = d; i0 = j; }
            else        { d1 = d;  i1 = j; }
          } else { d2 = d; i2 = j; }
        } else { d3 = d; i3 = j; }
      }
    }
  }
  int4 r; r.x = i0; r.y = i1; r.z = i2; r.w = i3;
  *reinterpret_cast<int4*>(&idx[((size_t)b * GD + q) * 4]) = r;
}

// ---------------- bf16 MFMA GEMM: out[b] = W(MxK) * Xt[b](NxK)^T ----------------
// 128x128 tile, BK=32, 256 threads = 4 waves, each wave 64x64 via 4x4 mfma_f32_16x16x32_bf16
template<bool OUT_BF16>
__global__ __launch_bounds__(256) void k_gemm(const ushort* __restrict__ W,
                                              const ushort* __restrict__ Xt,
                                              void* __restrict__ outv,
                                              int M, int Kd, int N) {
  __shared__ __align__(16) ushort As[128 * 40];  // +8 pad: 2-way-max bank aliasing on b128 reads
  __shared__ __align__(16) ushort Bs[128 * 40];
  int b = blockIdx.z;
  const ushort* X = Xt + (size_t)b * N * Kd;
  int m0 = blockIdx.y * 128, n0 = blockIdx.x * 128;
  int tid = threadIdx.x;
  int w = tid >> 6, lane = tid & 63;
  int lr = lane & 15, lq = lane >> 4;
  int mw = (w >> 1) * 64, nw = (w & 1) * 64;
  int r0 = tid >> 2, c0 = tid & 3;

  f32x4 zero = {0.f, 0.f, 0.f, 0.f};
  f32x4 acc[4][4];
#pragma unroll
  for (int mi = 0; mi < 4; mi++)
#pragma unroll
    for (int ni = 0; ni < 4; ni++) acc[mi][ni] = zero;

  int nk = Kd / 32;
  for (int kt = 0; kt < nk; kt++) {
    int kk = kt * 32;
    __syncthreads();
    uint4 va0 = *reinterpret_cast<const uint4*>(W + (size_t)(m0 + r0) * Kd + kk + c0 * 8);
    uint4 va1 = *reinterpret_cast<const uint4*>(W + (size_t)(m0 + r0 + 64) * Kd + kk + c0 * 8);
    uint4 vb0 = *reinterpret_cast<const uint4*>(X + (size_t)(n0 + r0) * Kd + kk + c0 * 8);
    uint4 vb1 = *reinterpret_cast<const uint4*>(X + (size_t)(n0 + r0 + 64) * Kd + kk + c0 * 8);
    *reinterpret_cast<uint4*>(&As[(r0)      * 40 + c0 * 8]) = va0;
    *reinterpret_cast<uint4*>(&As[(r0 + 64) * 40 + c0 * 8]) = va1;
    *reinterpret_cast<uint4*>(&Bs[(r0)      * 40 + c0 * 8]) = vb0;
    *reinterpret_cast<uint4*>(&Bs[(r0 + 64) * 40 + c0 * 8]) = vb1;
    __syncthreads();
    bf16x8 af[4], bfr[4];
#pragma unroll
    for (int mi = 0; mi < 4; mi++)
      af[mi] = *reinterpret_cast<const bf16x8*>(&As[(mw + mi * 16 + lr) * 40 + lq * 8]);
#pragma unroll
    for (int ni = 0; ni < 4; ni++)
      bfr[ni] = *reinterpret_cast<const bf16x8*>(&Bs[(nw + ni * 16 + lr) * 40 + lq * 8]);
#pragma unroll
    for (int mi = 0; mi < 4; mi++)
#pragma unroll
      for (int ni = 0; ni < 4; ni++)
        acc[mi][ni] = __builtin_amdgcn_mfma_f32_16x16x32_bf16(af[mi], bfr[ni], acc[mi][ni], 0, 0, 0);
  }
#pragma unroll
  for (int mi = 0; mi < 4; mi++) {
    int m = m0 + mw + mi * 16 + lq * 4;
#pragma unroll
    for (int ni = 0; ni < 4; ni++) {
      int n = n0 + nw + ni * 16 + lr;
#pragma unroll
      for (int r = 0; r < 4; r++) {
        size_t off = (size_t)b * M * N + (size_t)(m + r) * N + n;
        if constexpr (OUT_BF16) ((ushort*)outv)[off] = f2bf(acc[mi][ni][r]);
        else                    ((float*)outv)[off] = acc[mi][ni][r];
      }
    }
  }
}

// ---------------- GN stats pass 1: y = bf16(A)[gather] + Bq ----------------
__global__ void k_stats1(const ushort* __restrict__ A, const float* __restrict__ Bq,
                         const int* __restrict__ idx1, float* __restrict__ part) {
  int s = blockIdx.x, grp = blockIdx.y, b = blockIdx.z;
  int tid = threadIdx.x;
  float sum = 0.f, ssq = 0.f;
  for (int oi = 0; oi < 16; oi++) {
    int o = grp * 128 + s * 16 + oi;
    const ushort* Ar = A + ((size_t)b * M1 + o) * GS;
    const float* Br = Bq + ((size_t)b * M1 + o) * GD;
    for (int g = tid; g < GD; g += 256) {
      int4 id = *reinterpret_cast<const int4*>(&idx1[((size_t)b * GD + g) * 4]);
      float base = Br[g];
      float y0 = bf2f(Ar[id.x & (GS - 1)]) + base;
      float y1 = bf2f(Ar[id.y & (GS - 1)]) + base;
      float y2 = bf2f(Ar[id.z & (GS - 1)]) + base;
      float y3 = bf2f(Ar[id.w & (GS - 1)]) + base;
      sum += y0 + y1 + y2 + y3;
      ssq += y0 * y0 + y1 * y1 + y2 * y2 + y3 * y3;
    }
  }
  __shared__ float rs[256], rq[256];
  rs[tid] = sum; rq[tid] = ssq;
  __syncthreads();
  for (int t = 128; t > 0; t >>= 1) {
    if (tid < t) { rs[tid] += rs[tid + t]; rq[tid] += rq[tid + t]; }
    __syncthreads();
  }
  if (tid == 0) {
    int key = ((b * 4 + grp) * 8 + s) * 2;
    part[key] = rs[0]; part[key + 1] = rq[0];
  }
}

// ---------------- GN stats pass 2 (fp32 A2/B2q, 96-ch groups, 12 ch/split) ----------------
__global__ void k_stats2(const float* __restrict__ A2, const float* __restrict__ B2q,
                         const int* __restrict__ idx2, float* __restrict__ part) {
  int s = blockIdx.x, grp = blockIdx.y, b = blockIdx.z;
  int tid = threadIdx.x;
  float sum = 0.f, ssq = 0.f;
  for (int oi = 0; oi < 12; oi++) {
    int o = grp * 96 + s * 12 + oi;
    const float* Ar = A2 + ((size_t)b * M2 + o) * GD;
    const float* Br = B2q + ((size_t)b * M2 + o) * GD;
    for (int g = tid; g < GD; g += 256) {
      int4 id = *reinterpret_cast<const int4*>(&idx2[((size_t)b * GD + g) * 4]);
      float base = Br[g];
      float y0 = Ar[id.x & (GD - 1)] + base;
      float y1 = Ar[id.y & (GD - 1)] + base;
      float y2 = Ar[id.z & (GD - 1)] + base;
      float y3 = Ar[id.w & (GD - 1)] + base;
      sum += y0 + y1 + y2 + y3;
      ssq += y0 * y0 + y1 * y1 + y2 * y2 + y3 * y3;
    }
  }
  __shared__ float rs[256], rq[256];
  rs[tid] = sum; rq[tid] = ssq;
  __syncthreads();
  for (int t = 128; t > 0; t >>= 1) {
    if (tid < t) { rs[tid] += rs[tid + t]; rq[tid] += rq[tid + t]; }
    __syncthreads();
  }
  if (tid == 0) {
    int key = ((b * 4 + grp) * 8 + s) * 2;
    part[key] = rs[0]; part[key + 1] = rq[0];
  }
}

__global__ void k_statsfin(const float* __restrict__ part, float* __restrict__ fin, float invN) {
  int t = threadIdx.x;  // 64 = 16 b * 4 groups
  float s = 0.f, q = 0.f;
  for (int i = 0; i < 8; i++) { s += part[(t * 8 + i) * 2]; q += part[(t * 8 + i) * 2 + 1]; }
  float mean = s * invN;
  float var = q * invN - mean * mean;
  float rstd = 1.0f / sqrtf(fmaxf(var, 0.0f) + EPS_);  // guard: never NaN
  fin[t * 2] = mean; fin[t * 2 + 1] = rstd;
}

// ---------------- h = max_k leaky(GN(y)); write transposed hT[b][g][o] (bf16) ----------------
__global__ void k_h(const ushort* __restrict__ A, const float* __restrict__ Bq,
                    const int* __restrict__ idx1, const float* __restrict__ fin,
                    const float* __restrict__ gam, const float* __restrict__ bet,
                    ushort* __restrict__ hT) {
  __shared__ ushort tile[64][66];  // pitch 66: conflict-free column reads
  int g0 = blockIdx.x * 64, o0 = blockIdx.y * 64, b = blockIdx.z;
  int tid = threadIdx.x;
  int gx = tid & 63, oy = tid >> 6;
  int g = g0 + gx;
  int4 id = *reinterpret_cast<const int4*>(&idx1[((size_t)b * GD + g) * 4]);
  id.x &= (GS - 1); id.y &= (GS - 1); id.z &= (GS - 1); id.w &= (GS - 1);
#pragma unroll
  for (int oi = 0; oi < 16; oi++) {
    int ol = oi * 4 + oy;
    int o = o0 + ol;
    const ushort* Ar = A + ((size_t)b * M1 + o) * GS;
    float base = Bq[((size_t)b * M1 + o) * GD + g];
    float mean = fin[(b * 4 + (o >> 7)) * 2];
    float rstd = fin[(b * 4 + (o >> 7)) * 2 + 1];
    float ga = gam[o], be = bet[o];
    float m = -1e30f;
    {
      float y = bf2f(Ar[id.x]) + base; float v = (y - mean) * rstd * ga + be;
      v = v >= 0.f ? v : NEG * v; m = fmaxf(m, v);
    }
    {
      float y = bf2f(Ar[id.y]) + base; float v = (y - mean) * rstd * ga + be;
      v = v >= 0.f ? v : NEG * v; m = fmaxf(m, v);
    }
    {
      float y = bf2f(Ar[id.z]) + base; float v = (y - mean) * rstd * ga + be;
      v = v >= 0.f ? v : NEG * v; m = fmaxf(m, v);
    }
    {
      float y = bf2f(Ar[id.w]) + base; float v = (y - mean) * rstd * ga + be;
      v = v >= 0.f ? v : NEG * v; m = fmaxf(m, v);
    }
    tile[ol][gx] = f2bf(m);
  }
  __syncthreads();
  int col = tid & 63, r4 = tid >> 6;
#pragma unroll
  for (int i = 0; i < 16; i++) {
    int gl = i * 4 + r4;
    hT[((size_t)b * GD + g0 + gl) * K2C + o0 + col] = tile[col][gl];
  }
}

// ---------------- final: out[b][o][g] = max_k leaky(GN2(A2[gather]+B2q)) -> f32 ----------------
__global__ void k_out(const float* __restrict__ A2, const float* __restrict__ B2q,
                      const int* __restrict__ idx2, const float* __restrict__ fin,
                      const float* __restrict__ gam, const float* __restrict__ bet,
                      float* __restrict__ out) {
  int b = blockIdx.z, o = blockIdx.y;
  int g = blockIdx.x * 256 + threadIdx.x;
  const float* Ar = A2 + ((size_t)b * M2 + o) * GD;
  float base = B2q[((size_t)b * M2 + o) * GD + g];
  int4 id = *reinterpret_cast<const int4*>(&idx2[((size_t)b * GD + g) * 4]);
  id.x &= (GD - 1); id.y &= (GD - 1); id.z &= (GD - 1); id.w &= (GD - 1);
  float mean = fin[(b * 4 + o / 96) * 2];
  float rstd = fin[(b * 4 + o / 96) * 2 + 1];
  float ga = gam[o], be = bet[o];
  float m = -1e30f;
  { float y = Ar[id.x] + base; float v = (y - mean) * rstd * ga + be; v = v >= 0.f ? v : NEG * v; m = fmaxf(m, v); }
  { float y = Ar[id.y] + base; float v = (y - mean) * rstd * ga + be; v = v >= 0.f ? v : NEG * v; m = fmaxf(m, v); }
  { float y = Ar[id.z] + base; float v = (y - mean) * rstd * ga + be; v = v >= 0.f ? v : NEG * v; m = fmaxf(m, v); }
  { float y = Ar[id.w] + base; float v = (y - mean) * rstd * ga + be; v = v >= 0.f ? v : NEG * v; m = fmaxf(m, v); }
  out[((size_t)b * M2 + o) * GD + g] = m;
}

extern "C" void kernel_launch(void* const* d_in, const int* in_sizes, int n_in,
                              void* d_out, int out_size, void* d_ws, size_t ws_size,
                              hipStream_t stream) {
  (void)in_sizes; (void)n_in; (void)out_size;
  const float* coor  = (const float*)d_in[0];  // [16][3][4096] f32
  const float* f     = (const float*)d_in[1];  // [16][384][4096]
  const float* coorq = (const float*)d_in[2];  // [16][3][1024]
  const float* fq    = (const float*)d_in[3];  // [16][384][1024]
  const float* W1    = (const float*)d_in[4];  // [512][768]
  const float* g1    = (const float*)d_in[5];
  const float* b1    = (const float*)d_in[6];
  const float* W2    = (const float*)d_in[7];  // [384][1024]
  const float* g2    = (const float*)d_in[8];
  const float* b2    = (const float*)d_in[9];

  // Required workspace ~182.5 MB (internal buffers unchanged; skip cleanly if short).
  if (ws_size < 182468608u) return;

  char* ws = (char*)d_ws;
  int*    idx1 = (int*)(ws + 0);            // 256 KB
  int*    idx2 = (int*)(ws + 0x40000);      // 256 KB
  float*  s1p  = (float*)(ws + 0x80000);    // 4 KB
  float*  s1f  = (float*)(ws + 0x81000);
  float*  s2p  = (float*)(ws + 0x82000);
  float*  s2f  = (float*)(ws + 0x83000);
  ushort* W1a  = (ushort*)(ws + 0x84000);           // 512*384 bf16
  ushort* W1d  = W1a + (size_t)512 * 384;
  ushort* W2a  = W1d + (size_t)512 * 384;           // 384*512
  ushort* W2d  = W2a + (size_t)384 * 512;
  ushort* fT   = W2d + (size_t)384 * 512;           // [16][4096][384] bf16, 50.33 MB
  ushort* fqT  = fT + (size_t)B_ * GS * CIN;        // [16][1024][384] bf16, 12.6 MB
  ushort* Abuf = fqT + (size_t)B_ * GD * CIN;       // [16][512][4096] bf16, 67.1 MB
  float*  Bq   = (float*)(Abuf + (size_t)B_ * M1 * GS);   // [16][512][1024] f32, 33.6 MB
  ushort* hT   = (ushort*)((char*)Bq + (size_t)B_ * M1 * GD * 4); // [16][1024][512] bf16, 16.8 MB
  float*  A2   = (float*)fT;                        // [16][384][1024] f32 (aliases dead fT)
  float*  B2q  = A2 + (size_t)B_ * M2 * GD;         // [16][384][1024] f32

  // 1. transposes (+f32->bf16 convert) + weight prep
  k_transpose<<<dim3(GS / 32, CIN / 32, B_), dim3(32, 8), 0, stream>>>(f, fT, CIN, GS);
  k_transpose<<<dim3(GD / 32, CIN / 32, B_), dim3(32, 8), 0, stream>>>(fq, fqT, CIN, GD);
  k_wprep<<<dim3(512 * 384 / 256), 256, 0, stream>>>(W1, W1a, W1d, 384);
  k_wprep<<<dim3(384 * 512 / 256), 256, 0, stream>>>(W2, W2a, W2d, 512);

  // 2. kNN index sets (fp32 coords, exact ref arithmetic; both depend only on coords)
  k_knn<GS><<<dim3(GD / 256, B_), 256, 0, stream>>>(coorq, coor, idx1);
  k_knn<GD><<<dim3(GD / 256, B_), 256, 0, stream>>>(coorq, coorq, idx2);

  // 3. block1 GEMMs: A = W1a*f (bf16 out), Bq = W1d*fq (f32 out)
  k_gemm<true ><<<dim3(GS / 128, M1 / 128, B_), 256, 0, stream>>>(W1a, fT, Abuf, M1, CIN, GS);
  k_gemm<false><<<dim3(GD / 128, M1 / 128, B_), 256, 0, stream>>>(W1d, fqT, Bq, M1, CIN, GD);

  // 4. GN1 stats + h (writes hT transposed for GEMM2)
  k_stats1<<<dim3(8, 4, B_), 256, 0, stream>>>(Abuf, Bq, idx1, s1p);
  k_statsfin<<<1, 64, 0, stream>>>(s1p, s1f, 1.0f / 524288.0f);
  k_h<<<dim3(GD / 64, M1 / 64, B_), 256, 0, stream>>>(Abuf, Bq, idx1, s1f, g1, b1, hT);

  // 5. block2 GEMMs (outputs alias dead fT region)
  k_gemm<false><<<dim3(GD / 128, M2 / 128, B_), 256, 0, stream>>>(W2a, hT, A2, M2, K2C, GD);
  k_gemm<false><<<dim3(GD / 128, M2 / 128, B_), 256, 0, stream>>>(W2d, hT, B2q, M2, K2C, GD);

  // 6. GN2 stats + final output (f32)
  k_stats2<<<dim3(8, 4, B_), 256, 0, stream>>>(A2, B2q, idx2, s2p);
  k_statsfin<<<1, 64, 0, stream>>>(s2p, s2f, 1.0f / 393216.0f);
  k_out<<<dim3(GD / 256, M2, B_), 256, 0, stream>>>(A2, B2q, idx2, s2f, g2, b2, (float*)d_out);
}

// Round 5
// 643.442 us; speedup vs baseline: 1.6518x; 1.6518x over previous
//
#include <hip/hip_runtime.h>
#include <stdint.h>

// Problem constants (DGCNN propagation). Inputs/outputs are FLOAT32 (per the
// reference's jnp.float32 setup_inputs); internals use bf16 MFMA (2% threshold).
#define B_   16
#define CIN  384     // C
#define GS   4096    // source points (power of 2 -> maskable)
#define GD   1024    // query points  (power of 2 -> maskable)
#define M1   512     // block1 out channels
#define K2C  512     // block2 in channels (= M1)
#define M2   384     // block2 out channels (= C)
#define NEG  0.2f
#define EPS_ 1e-5f

typedef __bf16 bf16x8 __attribute__((ext_vector_type(8)));
typedef float  f32x4  __attribute__((ext_vector_type(4)));

__device__ __forceinline__ float bf2f(ushort u) {
  uint32_t v = ((uint32_t)u) << 16;
  return __builtin_bit_cast(float, v);
}
__device__ __forceinline__ ushort f2bf(float f) {
  uint32_t x = __builtin_bit_cast(uint32_t, f);
  x += 0x7FFFu + ((x >> 16) & 1u);
  return (ushort)(x >> 16);
}

// ---------------- transpose+convert [b][C][N] f32 -> [b][N][C] bf16 ----------------
__global__ void k_transpose(const float* __restrict__ src, ushort* __restrict__ dst,
                            int Cdim, int N) {
  __shared__ ushort tile[32][33];
  int b = blockIdx.z;
  int n0 = blockIdx.x * 32, c0 = blockIdx.y * 32;
  const float* s = src + (size_t)b * Cdim * N;
  ushort* d = dst + (size_t)b * Cdim * N;
  int tx = threadIdx.x, ty = threadIdx.y;
#pragma unroll
  for (int i = 0; i < 4; i++) {
    int c = c0 + ty + i * 8;
    tile[ty + i * 8][tx] = f2bf(s[(size_t)c * N + n0 + tx]);
  }
  __syncthreads();
#pragma unroll
  for (int i = 0; i < 4; i++) {
    int n = n0 + ty + i * 8;
    d[(size_t)n * Cdim + c0 + tx] = tile[tx][ty + i * 8];
  }
}

// ---------------- weight prep: Wa = bf16(W[:, :Kh]), Wd = bf16(W[:, Kh:] - W[:, :Kh]) ----------------
__global__ void k_wprep(const float* __restrict__ W, ushort* __restrict__ Wa,
                        ushort* __restrict__ Wd, int Khalf) {
  int t = blockIdx.x * 256 + threadIdx.x;
  int o = t / Khalf, c = t % Khalf;
  float wa = W[(size_t)o * 2 * Khalf + c];
  float wb = W[(size_t)o * 2 * Khalf + Khalf + c];
  Wa[t] = f2bf(wa);
  Wd[t] = f2bf(wb - wa);
}

// ---------------- kNN: wave-per-query, shfl-butterfly top-4 merge ----------------
// Distance formula + op order bit-identical to the verified serial version
// (contract off, (q2+s2)-2*dot). Selection = 4 smallest by (d, idx) lex,
// which equals jax.lax.top_k's lowest-index tie-break.
__device__ __forceinline__ void knn_lmin(float& ad, int& ai, float bd, int bi) {
  bool bl = (bd < ad) || (bd == ad && bi < ai);
  ad = bl ? bd : ad; ai = bl ? bi : ai;
}
__device__ __forceinline__ void knn_ce(float& ad, int& ai, float& bd, int& bi) {
  bool bl = (bd < ad) || (bd == ad && bi < ai);
  float na = bl ? bd : ad, nb = bl ? ad : bd;
  int nia = bl ? bi : ai, nib = bl ? ai : bi;
  ad = na; bd = nb; ai = nia; bi = nib;
}

template<int GSRC>
__global__ __launch_bounds__(256) void k_knn(const float* __restrict__ cq,
                                             const float* __restrict__ ck,
                                             int* __restrict__ idx) {
#pragma clang fp contract(off)
  int tid = threadIdx.x;
  int lane = tid & 63, wv = tid >> 6;
  int b = blockIdx.y;
  int q = blockIdx.x * 4 + wv;          // one wave per query
  const float* cqb = cq + (size_t)b * 3 * GD;
  const float* ckb = ck + (size_t)b * 3 * GSRC;
  float qx = cqb[q], qy = cqb[GD + q], qz = cqb[2 * GD + q];
  float q2 = (qx * qx + qy * qy) + qz * qz;

  float d0 = 1e30f, d1 = 1e30f, d2 = 1e30f, d3 = 1e30f;
  int i0 = 0x7FFFFFFF, i1 = 0x7FFFFFFF, i2 = 0x7FFFFFFF, i3 = 0x7FFFFFFF;
  for (int j = lane; j < GSRC; j += 64) {   // per-lane indices ascending
    float x = ckb[j], y = ckb[GSRC + j], z = ckb[2 * GSRC + j];
    float s2 = (x * x + y * y) + z * z;
    float dot = (qx * x + qy * y) + qz * z;
    float d = (q2 + s2) - 2.0f * dot;
    if (d < d3) {
      if (d < d2) {
        d3 = d2; i3 = i2;
        if (d < d1) {
          d2 = d1; i2 = i1;
          if (d < d0) { d1 = d0; i1 = i0; d0 = d; i0 = j; }
          else        { d1 = d;  i1 = j; }
        } else { d2 = d; i2 = j; }
      } else { d3 = d; i3 = j; }
    }
  }
  // 6-step butterfly: merge two sorted 4-lists -> lowest 4 (bitonic, lex order)
#pragma unroll
  for (int off = 1; off < 64; off <<= 1) {
    float pd0 = __shfl_xor(d0, off), pd1 = __shfl_xor(d1, off);
    float pd2 = __shfl_xor(d2, off), pd3 = __shfl_xor(d3, off);
    int pi0 = __shfl_xor(i0, off), pi1 = __shfl_xor(i1, off);
    int pi2 = __shfl_xor(i2, off), pi3 = __shfl_xor(i3, off);
    // stage 1 of bitonic merge on [a0..a3, b3..b0]: keep lower half
    knn_lmin(d0, i0, pd3, pi3);
    knn_lmin(d1, i1, pd2, pi2);
    knn_lmin(d2, i2, pd1, pi1);
    knn_lmin(d3, i3, pd0, pi0);
    // sort the bitonic lower half
    knn_ce(d0, i0, d2, i2);
    knn_ce(d1, i1, d3, i3);
    knn_ce(d0, i0, d1, i1);
    knn_ce(d2, i2, d3, i3);
  }
  if (lane == 0) {
    int4 r; r.x = i0; r.y = i1; r.z = i2; r.w = i3;
    *reinterpret_cast<int4*>(&idx[((size_t)b * GD + q) * 4]) = r;
  }
}

// ---------------- bf16 MFMA GEMM: out[b] = W(MxK) * Xt[b](NxK)^T ----------------
// 128x128 tile, BK=32, 256 threads = 4 waves, each wave 64x64 via 4x4 mfma_f32_16x16x32_bf16
template<bool OUT_BF16>
__global__ __launch_bounds__(256) void k_gemm(const ushort* __restrict__ W,
                                              const ushort* __restrict__ Xt,
                                              void* __restrict__ outv,
                                              int M, int Kd, int N) {
  __shared__ __align__(16) ushort As[128 * 40];  // +8 pad: 2-way-max bank aliasing on b128 reads
  __shared__ __align__(16) ushort Bs[128 * 40];
  int b = blockIdx.z;
  const ushort* X = Xt + (size_t)b * N * Kd;
  int m0 = blockIdx.y * 128, n0 = blockIdx.x * 128;
  int tid = threadIdx.x;
  int w = tid >> 6, lane = tid & 63;
  int lr = lane & 15, lq = lane >> 4;
  int mw = (w >> 1) * 64, nw = (w & 1) * 64;
  int r0 = tid >> 2, c0 = tid & 3;

  f32x4 zero = {0.f, 0.f, 0.f, 0.f};
  f32x4 acc[4][4];
#pragma unroll
  for (int mi = 0; mi < 4; mi++)
#pragma unroll
    for (int ni = 0; ni < 4; ni++) acc[mi][ni] = zero;

  int nk = Kd / 32;
  for (int kt = 0; kt < nk; kt++) {
    int kk = kt * 32;
    __syncthreads();
    uint4 va0 = *reinterpret_cast<const uint4*>(W + (size_t)(m0 + r0) * Kd + kk + c0 * 8);
    uint4 va1 = *reinterpret_cast<const uint4*>(W + (size_t)(m0 + r0 + 64) * Kd + kk + c0 * 8);
    uint4 vb0 = *reinterpret_cast<const uint4*>(X + (size_t)(n0 + r0) * Kd + kk + c0 * 8);
    uint4 vb1 = *reinterpret_cast<const uint4*>(X + (size_t)(n0 + r0 + 64) * Kd + kk + c0 * 8);
    *reinterpret_cast<uint4*>(&As[(r0)      * 40 + c0 * 8]) = va0;
    *reinterpret_cast<uint4*>(&As[(r0 + 64) * 40 + c0 * 8]) = va1;
    *reinterpret_cast<uint4*>(&Bs[(r0)      * 40 + c0 * 8]) = vb0;
    *reinterpret_cast<uint4*>(&Bs[(r0 + 64) * 40 + c0 * 8]) = vb1;
    __syncthreads();
    bf16x8 af[4], bfr[4];
#pragma unroll
    for (int mi = 0; mi < 4; mi++)
      af[mi] = *reinterpret_cast<const bf16x8*>(&As[(mw + mi * 16 + lr) * 40 + lq * 8]);
#pragma unroll
    for (int ni = 0; ni < 4; ni++)
      bfr[ni] = *reinterpret_cast<const bf16x8*>(&Bs[(nw + ni * 16 + lr) * 40 + lq * 8]);
#pragma unroll
    for (int mi = 0; mi < 4; mi++)
#pragma unroll
      for (int ni = 0; ni < 4; ni++)
        acc[mi][ni] = __builtin_amdgcn_mfma_f32_16x16x32_bf16(af[mi], bfr[ni], acc[mi][ni], 0, 0, 0);
  }
#pragma unroll
  for (int mi = 0; mi < 4; mi++) {
    int m = m0 + mw + mi * 16 + lq * 4;
#pragma unroll
    for (int ni = 0; ni < 4; ni++) {
      int n = n0 + nw + ni * 16 + lr;
#pragma unroll
      for (int r = 0; r < 4; r++) {
        size_t off = (size_t)b * M * N + (size_t)(m + r) * N + n;
        if constexpr (OUT_BF16) ((ushort*)outv)[off] = f2bf(acc[mi][ni][r]);
        else                    ((float*)outv)[off] = acc[mi][ni][r];
      }
    }
  }
}

// ---------------- GN stats pass 1: y = bf16(A)[gather] + Bq ----------------
__global__ void k_stats1(const ushort* __restrict__ A, const float* __restrict__ Bq,
                         const int* __restrict__ idx1, float* __restrict__ part) {
  int s = blockIdx.x, grp = blockIdx.y, b = blockIdx.z;
  int tid = threadIdx.x;
  float sum = 0.f, ssq = 0.f;
  for (int oi = 0; oi < 16; oi++) {
    int o = grp * 128 + s * 16 + oi;
    const ushort* Ar = A + ((size_t)b * M1 + o) * GS;
    const float* Br = Bq + ((size_t)b * M1 + o) * GD;
    for (int g = tid; g < GD; g += 256) {
      int4 id = *reinterpret_cast<const int4*>(&idx1[((size_t)b * GD + g) * 4]);
      float base = Br[g];
      float y0 = bf2f(Ar[id.x & (GS - 1)]) + base;
      float y1 = bf2f(Ar[id.y & (GS - 1)]) + base;
      float y2 = bf2f(Ar[id.z & (GS - 1)]) + base;
      float y3 = bf2f(Ar[id.w & (GS - 1)]) + base;
      sum += y0 + y1 + y2 + y3;
      ssq += y0 * y0 + y1 * y1 + y2 * y2 + y3 * y3;
    }
  }
  __shared__ float rs[256], rq[256];
  rs[tid] = sum; rq[tid] = ssq;
  __syncthreads();
  for (int t = 128; t > 0; t >>= 1) {
    if (tid < t) { rs[tid] += rs[tid + t]; rq[tid] += rq[tid + t]; }
    __syncthreads();
  }
  if (tid == 0) {
    int key = ((b * 4 + grp) * 8 + s) * 2;
    part[key] = rs[0]; part[key + 1] = rq[0];
  }
}

// ---------------- GN stats pass 2 (fp32 A2/B2q, 96-ch groups, 12 ch/split) ----------------
__global__ void k_stats2(const float* __restrict__ A2, const float* __restrict__ B2q,
                         const int* __restrict__ idx2, float* __restrict__ part) {
  int s = blockIdx.x, grp = blockIdx.y, b = blockIdx.z;
  int tid = threadIdx.x;
  float sum = 0.f, ssq = 0.f;
  for (int oi = 0; oi < 12; oi++) {
    int o = grp * 96 + s * 12 + oi;
    const float* Ar = A2 + ((size_t)b * M2 + o) * GD;
    const float* Br = B2q + ((size_t)b * M2 + o) * GD;
    for (int g = tid; g < GD; g += 256) {
      int4 id = *reinterpret_cast<const int4*>(&idx2[((size_t)b * GD + g) * 4]);
      float base = Br[g];
      float y0 = Ar[id.x & (GD - 1)] + base;
      float y1 = Ar[id.y & (GD - 1)] + base;
      float y2 = Ar[id.z & (GD - 1)] + base;
      float y3 = Ar[id.w & (GD - 1)] + base;
      sum += y0 + y1 + y2 + y3;
      ssq += y0 * y0 + y1 * y1 + y2 * y2 + y3 * y3;
    }
  }
  __shared__ float rs[256], rq[256];
  rs[tid] = sum; rq[tid] = ssq;
  __syncthreads();
  for (int t = 128; t > 0; t >>= 1) {
    if (tid < t) { rs[tid] += rs[tid + t]; rq[tid] += rq[tid + t]; }
    __syncthreads();
  }
  if (tid == 0) {
    int key = ((b * 4 + grp) * 8 + s) * 2;
    part[key] = rs[0]; part[key + 1] = rq[0];
  }
}

__global__ void k_statsfin(const float* __restrict__ part, float* __restrict__ fin, float invN) {
  int t = threadIdx.x;  // 64 = 16 b * 4 groups
  float s = 0.f, q = 0.f;
  for (int i = 0; i < 8; i++) { s += part[(t * 8 + i) * 2]; q += part[(t * 8 + i) * 2 + 1]; }
  float mean = s * invN;
  float var = q * invN - mean * mean;
  float rstd = 1.0f / sqrtf(fmaxf(var, 0.0f) + EPS_);  // guard: never NaN
  fin[t * 2] = mean; fin[t * 2 + 1] = rstd;
}

// ---------------- h = max_k leaky(GN(y)); write transposed hT[b][g][o] (bf16) ----------------
__global__ void k_h(const ushort* __restrict__ A, const float* __restrict__ Bq,
                    const int* __restrict__ idx1, const float* __restrict__ fin,
                    const float* __restrict__ gam, const float* __restrict__ bet,
                    ushort* __restrict__ hT) {
  __shared__ ushort tile[64][66];  // pitch 66: conflict-free column reads
  int g0 = blockIdx.x * 64, o0 = blockIdx.y * 64, b = blockIdx.z;
  int tid = threadIdx.x;
  int gx = tid & 63, oy = tid >> 6;
  int g = g0 + gx;
  int4 id = *reinterpret_cast<const int4*>(&idx1[((size_t)b * GD + g) * 4]);
  id.x &= (GS - 1); id.y &= (GS - 1); id.z &= (GS - 1); id.w &= (GS - 1);
#pragma unroll
  for (int oi = 0; oi < 16; oi++) {
    int ol = oi * 4 + oy;
    int o = o0 + ol;
    const ushort* Ar = A + ((size_t)b * M1 + o) * GS;
    float base = Bq[((size_t)b * M1 + o) * GD + g];
    float mean = fin[(b * 4 + (o >> 7)) * 2];
    float rstd = fin[(b * 4 + (o >> 7)) * 2 + 1];
    float ga = gam[o], be = bet[o];
    float m = -1e30f;
    {
      float y = bf2f(Ar[id.x]) + base; float v = (y - mean) * rstd * ga + be;
      v = v >= 0.f ? v : NEG * v; m = fmaxf(m, v);
    }
    {
      float y = bf2f(Ar[id.y]) + base; float v = (y - mean) * rstd * ga + be;
      v = v >= 0.f ? v : NEG * v; m = fmaxf(m, v);
    }
    {
      float y = bf2f(Ar[id.z]) + base; float v = (y - mean) * rstd * ga + be;
      v = v >= 0.f ? v : NEG * v; m = fmaxf(m, v);
    }
    {
      float y = bf2f(Ar[id.w]) + base; float v = (y - mean) * rstd * ga + be;
      v = v >= 0.f ? v : NEG * v; m = fmaxf(m, v);
    }
    tile[ol][gx] = f2bf(m);
  }
  __syncthreads();
  int col = tid & 63, r4 = tid >> 6;
#pragma unroll
  for (int i = 0; i < 16; i++) {
    int gl = i * 4 + r4;
    hT[((size_t)b * GD + g0 + gl) * K2C + o0 + col] = tile[col][gl];
  }
}

// ---------------- final: out[b][o][g] = max_k leaky(GN2(A2[gather]+B2q)) -> f32 ----------------
__global__ void k_out(const float* __restrict__ A2, const float* __restrict__ B2q,
                      const int* __restrict__ idx2, const float* __restrict__ fin,
                      const float* __restrict__ gam, const float* __restrict__ bet,
                      float* __restrict__ out) {
  int b = blockIdx.z, o = blockIdx.y;
  int g = blockIdx.x * 256 + threadIdx.x;
  const float* Ar = A2 + ((size_t)b * M2 + o) * GD;
  float base = B2q[((size_t)b * M2 + o) * GD + g];
  int4 id = *reinterpret_cast<const int4*>(&idx2[((size_t)b * GD + g) * 4]);
  id.x &= (GD - 1); id.y &= (GD - 1); id.z &= (GD - 1); id.w &= (GD - 1);
  float mean = fin[(b * 4 + o / 96) * 2];
  float rstd = fin[(b * 4 + o / 96) * 2 + 1];
  float ga = gam[o], be = bet[o];
  float m = -1e30f;
  { float y = Ar[id.x] + base; float v = (y - mean) * rstd * ga + be; v = v >= 0.f ? v : NEG * v; m = fmaxf(m, v); }
  { float y = Ar[id.y] + base; float v = (y - mean) * rstd * ga + be; v = v >= 0.f ? v : NEG * v; m = fmaxf(m, v); }
  { float y = Ar[id.z] + base; float v = (y - mean) * rstd * ga + be; v = v >= 0.f ? v : NEG * v; m = fmaxf(m, v); }
  { float y = Ar[id.w] + base; float v = (y - mean) * rstd * ga + be; v = v >= 0.f ? v : NEG * v; m = fmaxf(m, v); }
  out[((size_t)b * M2 + o) * GD + g] = m;
}

extern "C" void kernel_launch(void* const* d_in, const int* in_sizes, int n_in,
                              void* d_out, int out_size, void* d_ws, size_t ws_size,
                              hipStream_t stream) {
  (void)in_sizes; (void)n_in; (void)out_size;
  const float* coor  = (const float*)d_in[0];  // [16][3][4096] f32
  const float* f     = (const float*)d_in[1];  // [16][384][4096]
  const float* coorq = (const float*)d_in[2];  // [16][3][1024]
  const float* fq    = (const float*)d_in[3];  // [16][384][1024]
  const float* W1    = (const float*)d_in[4];  // [512][768]
  const float* g1    = (const float*)d_in[5];
  const float* b1    = (const float*)d_in[6];
  const float* W2    = (const float*)d_in[7];  // [384][1024]
  const float* g2    = (const float*)d_in[8];
  const float* b2    = (const float*)d_in[9];

  // Required workspace ~182.5 MB (internal buffers unchanged; skip cleanly if short).
  if (ws_size < 182468608u) return;

  char* ws = (char*)d_ws;
  int*    idx1 = (int*)(ws + 0);            // 256 KB
  int*    idx2 = (int*)(ws + 0x40000);      // 256 KB
  float*  s1p  = (float*)(ws + 0x80000);    // 4 KB
  float*  s1f  = (float*)(ws + 0x81000);
  float*  s2p  = (float*)(ws + 0x82000);
  float*  s2f  = (float*)(ws + 0x83000);
  ushort* W1a  = (ushort*)(ws + 0x84000);           // 512*384 bf16
  ushort* W1d  = W1a + (size_t)512 * 384;
  ushort* W2a  = W1d + (size_t)512 * 384;           // 384*512
  ushort* W2d  = W2a + (size_t)384 * 512;
  ushort* fT   = W2d + (size_t)384 * 512;           // [16][4096][384] bf16, 50.33 MB
  ushort* fqT  = fT + (size_t)B_ * GS * CIN;        // [16][1024][384] bf16, 12.6 MB
  ushort* Abuf = fqT + (size_t)B_ * GD * CIN;       // [16][512][4096] bf16, 67.1 MB
  float*  Bq   = (float*)(Abuf + (size_t)B_ * M1 * GS);   // [16][512][1024] f32, 33.6 MB
  ushort* hT   = (ushort*)((char*)Bq + (size_t)B_ * M1 * GD * 4); // [16][1024][512] bf16, 16.8 MB
  float*  A2   = (float*)fT;                        // [16][384][1024] f32 (aliases dead fT)
  float*  B2q  = A2 + (size_t)B_ * M2 * GD;         // [16][384][1024] f32

  // 1. transposes (+f32->bf16 convert) + weight prep
  k_transpose<<<dim3(GS / 32, CIN / 32, B_), dim3(32, 8), 0, stream>>>(f, fT, CIN, GS);
  k_transpose<<<dim3(GD / 32, CIN / 32, B_), dim3(32, 8), 0, stream>>>(fq, fqT, CIN, GD);
  k_wprep<<<dim3(512 * 384 / 256), 256, 0, stream>>>(W1, W1a, W1d, 384);
  k_wprep<<<dim3(384 * 512 / 256), 256, 0, stream>>>(W2, W2a, W2d, 512);

  // 2. kNN index sets (wave-per-query; both depend only on coords)
  k_knn<GS><<<dim3(GD / 4, B_), 256, 0, stream>>>(coorq, coor, idx1);
  k_knn<GD><<<dim3(GD / 4, B_), 256, 0, stream>>>(coorq, coorq, idx2);

  // 3. block1 GEMMs: A = W1a*f (bf16 out), Bq = W1d*fq (f32 out)
  k_gemm<true ><<<dim3(GS / 128, M1 / 128, B_), 256, 0, stream>>>(W1a, fT, Abuf, M1, CIN, GS);
  k_gemm<false><<<dim3(GD / 128, M1 / 128, B_), 256, 0, stream>>>(W1d, fqT, Bq, M1, CIN, GD);

  // 4. GN1 stats + h (writes hT transposed for GEMM2)
  k_stats1<<<dim3(8, 4, B_), 256, 0, stream>>>(Abuf, Bq, idx1, s1p);
  k_statsfin<<<1, 64, 0, stream>>>(s1p, s1f, 1.0f / 524288.0f);
  k_h<<<dim3(GD / 64, M1 / 64, B_), 256, 0, stream>>>(Abuf, Bq, idx1, s1f, g1, b1, hT);

  // 5. block2 GEMMs (outputs alias dead fT region)
  k_gemm<false><<<dim3(GD / 128, M2 / 128, B_), 256, 0, stream>>>(W2a, hT, A2, M2, K2C, GD);
  k_gemm<false><<<dim3(GD / 128, M2 / 128, B_), 256, 0, stream>>>(W2d, hT, B2q, M2, K2C, GD);

  // 6. GN2 stats + final output (f32)
  k_stats2<<<dim3(8, 4, B_), 256, 0, stream>>>(A2, B2q, idx2, s2p);
  k_statsfin<<<1, 64, 0, stream>>>(s2p, s2f, 1.0f / 393216.0f);
  k_out<<<dim3(GD / 256, M2, B_), 256, 0, stream>>>(A2, B2q, idx2, s2f, g2, b2, (float*)d_out);
}

// Round 6
// 589.349 us; speedup vs baseline: 1.8034x; 1.0918x over previous
//
#include <hip/hip_runtime.h>
#include <stdint.h>

// Problem constants (DGCNN propagation). Inputs/outputs are FLOAT32 (per the
// reference's jnp.float32 setup_inputs); internals use bf16 MFMA (2% threshold).
#define B_   16
#define CIN  384     // C
#define GS   4096    // source points (power of 2 -> maskable)
#define GD   1024    // query points  (power of 2 -> maskable)
#define M1   512     // block1 out channels
#define K2C  512     // block2 in channels (= M1)
#define M2   384     // block2 out channels (= C)
#define NEG  0.2f
#define EPS_ 1e-5f

typedef __bf16 bf16x8 __attribute__((ext_vector_type(8)));
typedef float  f32x4  __attribute__((ext_vector_type(4)));

__device__ __forceinline__ float bf2f(ushort u) {
  uint32_t v = ((uint32_t)u) << 16;
  return __builtin_bit_cast(float, v);
}
__device__ __forceinline__ ushort f2bf(float f) {
  uint32_t x = __builtin_bit_cast(uint32_t, f);
  x += 0x7FFFu + ((x >> 16) & 1u);
  return (ushort)(x >> 16);
}

// ---------------- transpose+convert [b][C][N] f32 -> [b][N][C] bf16 ----------------
__global__ void k_transpose(const float* __restrict__ src, ushort* __restrict__ dst,
                            int Cdim, int N) {
  __shared__ ushort tile[32][33];
  int b = blockIdx.z;
  int n0 = blockIdx.x * 32, c0 = blockIdx.y * 32;
  const float* s = src + (size_t)b * Cdim * N;
  ushort* d = dst + (size_t)b * Cdim * N;
  int tx = threadIdx.x, ty = threadIdx.y;
#pragma unroll
  for (int i = 0; i < 4; i++) {
    int c = c0 + ty + i * 8;
    tile[ty + i * 8][tx] = f2bf(s[(size_t)c * N + n0 + tx]);
  }
  __syncthreads();
#pragma unroll
  for (int i = 0; i < 4; i++) {
    int n = n0 + ty + i * 8;
    d[(size_t)n * Cdim + c0 + tx] = tile[tx][ty + i * 8];
  }
}

// ---------------- weight prep: Wa = bf16(W[:, :Kh]), Wd = bf16(W[:, Kh:] - W[:, :Kh]) ----------------
__global__ void k_wprep(const float* __restrict__ W, ushort* __restrict__ Wa,
                        ushort* __restrict__ Wd, int Khalf) {
  int t = blockIdx.x * 256 + threadIdx.x;
  int o = t / Khalf, c = t % Khalf;
  float wa = W[(size_t)o * 2 * Khalf + c];
  float wb = W[(size_t)o * 2 * Khalf + Khalf + c];
  Wa[t] = f2bf(wa);
  Wd[t] = f2bf(wb - wa);
}

// ---------------- kNN: wave-per-query, branchless top-4, shfl-butterfly merge ----------------
// Distance formula + op order bit-identical to the verified round-4 serial version
// (contract off, (q2+s2)-2*dot). Branchless strict-< insert + ascending per-lane
// scan order == branchy version's selection exactly (ties keep earlier index);
// cross-lane merge by (d, idx) lex == jax.lax.top_k lowest-index tie-break.
__device__ __forceinline__ void knn_lmin(float& ad, int& ai, float bd, int bi) {
  bool bl = (bd < ad) || (bd == ad && bi < ai);
  ad = bl ? bd : ad; ai = bl ? bi : ai;
}
__device__ __forceinline__ void knn_ce(float& ad, int& ai, float& bd, int& bi) {
  bool bl = (bd < ad) || (bd == ad && bi < ai);
  float na = bl ? bd : ad, nb = bl ? ad : bd;
  int nia = bl ? bi : ai, nib = bl ? ai : bi;
  ad = na; bd = nb; ai = nia; bi = nib;
}

template<int GSRC>
__global__ __launch_bounds__(256) void k_knn(const float* __restrict__ cq,
                                             const float* __restrict__ ck,
                                             int* __restrict__ idx) {
#pragma clang fp contract(off)
  int tid = threadIdx.x;
  int lane = tid & 63, wv = tid >> 6;
  int b = blockIdx.y;
  int q = blockIdx.x * 4 + wv;          // one wave per query
  const float* cqb = cq + (size_t)b * 3 * GD;
  const float* ckb = ck + (size_t)b * 3 * GSRC;
  float qx = cqb[q], qy = cqb[GD + q], qz = cqb[2 * GD + q];
  float q2 = (qx * qx + qy * qy) + qz * qz;

  float d0 = 1e30f, d1 = 1e30f, d2 = 1e30f, d3 = 1e30f;
  int i0 = 0x7FFFFFFF, i1 = 0x7FFFFFFF, i2 = 0x7FFFFFFF, i3 = 0x7FFFFFFF;
  for (int j0 = lane * 4; j0 < GSRC; j0 += 256) {   // per-lane indices ascending
    float4 X = *reinterpret_cast<const float4*>(ckb + j0);
    float4 Y = *reinterpret_cast<const float4*>(ckb + GSRC + j0);
    float4 Z = *reinterpret_cast<const float4*>(ckb + 2 * GSRC + j0);
#pragma unroll
    for (int u = 0; u < 4; u++) {
      float x = (&X.x)[u], y = (&Y.x)[u], z = (&Z.x)[u];
      float s2 = (x * x + y * y) + z * z;
      float dot = (qx * x + qy * y) + qz * z;
      float d = (q2 + s2) - 2.0f * dot;
      int j = j0 + u;
      // branchless sorted insert (strict < everywhere)
      bool c = d < d3;
      d3 = c ? d : d3; i3 = c ? j : i3;
      c = d3 < d2; { float t = d3; d3 = c ? d2 : d3; d2 = c ? t : d2;
                     int ti = i3; i3 = c ? i2 : i3; i2 = c ? ti : i2; }
      c = d2 < d1; { float t = d2; d2 = c ? d1 : d2; d1 = c ? t : d1;
                     int ti = i2; i2 = c ? i1 : i2; i1 = c ? ti : i1; }
      c = d1 < d0; { float t = d1; d1 = c ? d0 : d1; d0 = c ? t : d0;
                     int ti = i1; i1 = c ? i0 : i1; i0 = c ? ti : i0; }
    }
  }
  // 6-step butterfly: merge two sorted 4-lists -> lowest 4 (bitonic, lex order)
#pragma unroll
  for (int off = 1; off < 64; off <<= 1) {
    float pd0 = __shfl_xor(d0, off), pd1 = __shfl_xor(d1, off);
    float pd2 = __shfl_xor(d2, off), pd3 = __shfl_xor(d3, off);
    int pi0 = __shfl_xor(i0, off), pi1 = __shfl_xor(i1, off);
    int pi2 = __shfl_xor(i2, off), pi3 = __shfl_xor(i3, off);
    knn_lmin(d0, i0, pd3, pi3);
    knn_lmin(d1, i1, pd2, pi2);
    knn_lmin(d2, i2, pd1, pi1);
    knn_lmin(d3, i3, pd0, pi0);
    knn_ce(d0, i0, d2, i2);
    knn_ce(d1, i1, d3, i3);
    knn_ce(d0, i0, d1, i1);
    knn_ce(d2, i2, d3, i3);
  }
  if (lane == 0) {
    int4 r; r.x = i0; r.y = i1; r.z = i2; r.w = i3;
    *reinterpret_cast<int4*>(&idx[((size_t)b * GD + q) * 4]) = r;
  }
}

// ---------------- bf16 MFMA GEMM: out[b] = W(MxK) * Xt[b](NxK)^T ----------------
// 128x128 tile, BK=32, 256 threads = 4 waves, each wave 64x64 via 4x4 mfma_f32_16x16x32_bf16
template<bool OUT_BF16>
__global__ __launch_bounds__(256) void k_gemm(const ushort* __restrict__ W,
                                              const ushort* __restrict__ Xt,
                                              void* __restrict__ outv,
                                              int M, int Kd, int N) {
  __shared__ __align__(16) ushort As[128 * 40];  // +8 pad: 2-way-max bank aliasing on b128 reads
  __shared__ __align__(16) ushort Bs[128 * 40];
  int b = blockIdx.z;
  const ushort* X = Xt + (size_t)b * N * Kd;
  int m0 = blockIdx.y * 128, n0 = blockIdx.x * 128;
  int tid = threadIdx.x;
  int w = tid >> 6, lane = tid & 63;
  int lr = lane & 15, lq = lane >> 4;
  int mw = (w >> 1) * 64, nw = (w & 1) * 64;
  int r0 = tid >> 2, c0 = tid & 3;

  f32x4 zero = {0.f, 0.f, 0.f, 0.f};
  f32x4 acc[4][4];
#pragma unroll
  for (int mi = 0; mi < 4; mi++)
#pragma unroll
    for (int ni = 0; ni < 4; ni++) acc[mi][ni] = zero;

  int nk = Kd / 32;
  for (int kt = 0; kt < nk; kt++) {
    int kk = kt * 32;
    __syncthreads();
    uint4 va0 = *reinterpret_cast<const uint4*>(W + (size_t)(m0 + r0) * Kd + kk + c0 * 8);
    uint4 va1 = *reinterpret_cast<const uint4*>(W + (size_t)(m0 + r0 + 64) * Kd + kk + c0 * 8);
    uint4 vb0 = *reinterpret_cast<const uint4*>(X + (size_t)(n0 + r0) * Kd + kk + c0 * 8);
    uint4 vb1 = *reinterpret_cast<const uint4*>(X + (size_t)(n0 + r0 + 64) * Kd + kk + c0 * 8);
    *reinterpret_cast<uint4*>(&As[(r0)      * 40 + c0 * 8]) = va0;
    *reinterpret_cast<uint4*>(&As[(r0 + 64) * 40 + c0 * 8]) = va1;
    *reinterpret_cast<uint4*>(&Bs[(r0)      * 40 + c0 * 8]) = vb0;
    *reinterpret_cast<uint4*>(&Bs[(r0 + 64) * 40 + c0 * 8]) = vb1;
    __syncthreads();
    bf16x8 af[4], bfr[4];
#pragma unroll
    for (int mi = 0; mi < 4; mi++)
      af[mi] = *reinterpret_cast<const bf16x8*>(&As[(mw + mi * 16 + lr) * 40 + lq * 8]);
#pragma unroll
    for (int ni = 0; ni < 4; ni++)
      bfr[ni] = *reinterpret_cast<const bf16x8*>(&Bs[(nw + ni * 16 + lr) * 40 + lq * 8]);
#pragma unroll
    for (int mi = 0; mi < 4; mi++)
#pragma unroll
      for (int ni = 0; ni < 4; ni++)
        acc[mi][ni] = __builtin_amdgcn_mfma_f32_16x16x32_bf16(af[mi], bfr[ni], acc[mi][ni], 0, 0, 0);
  }
#pragma unroll
  for (int mi = 0; mi < 4; mi++) {
    int m = m0 + mw + mi * 16 + lq * 4;
#pragma unroll
    for (int ni = 0; ni < 4; ni++) {
      int n = n0 + nw + ni * 16 + lr;
#pragma unroll
      for (int r = 0; r < 4; r++) {
        size_t off = (size_t)b * M * N + (size_t)(m + r) * N + n;
        if constexpr (OUT_BF16) ((ushort*)outv)[off] = f2bf(acc[mi][ni][r]);
        else                    ((float*)outv)[off] = acc[mi][ni][r];
      }
    }
  }
}

// ---------------- GN stats pass 1: y = bf16(A)[gather] + Bq ----------------
__global__ void k_stats1(const ushort* __restrict__ A, const float* __restrict__ Bq,
                         const int* __restrict__ idx1, float* __restrict__ part) {
  int s = blockIdx.x, grp = blockIdx.y, b = blockIdx.z;
  int tid = threadIdx.x;
  float sum = 0.f, ssq = 0.f;
  for (int oi = 0; oi < 16; oi++) {
    int o = grp * 128 + s * 16 + oi;
    const ushort* Ar = A + ((size_t)b * M1 + o) * GS;
    const float* Br = Bq + ((size_t)b * M1 + o) * GD;
    for (int g = tid; g < GD; g += 256) {
      int4 id = *reinterpret_cast<const int4*>(&idx1[((size_t)b * GD + g) * 4]);
      float base = Br[g];
      float y0 = bf2f(Ar[id.x & (GS - 1)]) + base;
      float y1 = bf2f(Ar[id.y & (GS - 1)]) + base;
      float y2 = bf2f(Ar[id.z & (GS - 1)]) + base;
      float y3 = bf2f(Ar[id.w & (GS - 1)]) + base;
      sum += y0 + y1 + y2 + y3;
      ssq += y0 * y0 + y1 * y1 + y2 * y2 + y3 * y3;
    }
  }
  __shared__ float rs[256], rq[256];
  rs[tid] = sum; rq[tid] = ssq;
  __syncthreads();
  for (int t = 128; t > 0; t >>= 1) {
    if (tid < t) { rs[tid] += rs[tid + t]; rq[tid] += rq[tid + t]; }
    __syncthreads();
  }
  if (tid == 0) {
    int key = ((b * 4 + grp) * 8 + s) * 2;
    part[key] = rs[0]; part[key + 1] = rq[0];
  }
}

// ---------------- GN stats pass 2 (fp32 A2/B2q, 96-ch groups, 12 ch/split) ----------------
__global__ void k_stats2(const float* __restrict__ A2, const float* __restrict__ B2q,
                         const int* __restrict__ idx2, float* __restrict__ part) {
  int s = blockIdx.x, grp = blockIdx.y, b = blockIdx.z;
  int tid = threadIdx.x;
  float sum = 0.f, ssq = 0.f;
  for (int oi = 0; oi < 12; oi++) {
    int o = grp * 96 + s * 12 + oi;
    const float* Ar = A2 + ((size_t)b * M2 + o) * GD;
    const float* Br = B2q + ((size_t)b * M2 + o) * GD;
    for (int g = tid; g < GD; g += 256) {
      int4 id = *reinterpret_cast<const int4*>(&idx2[((size_t)b * GD + g) * 4]);
      float base = Br[g];
      float y0 = Ar[id.x & (GD - 1)] + base;
      float y1 = Ar[id.y & (GD - 1)] + base;
      float y2 = Ar[id.z & (GD - 1)] + base;
      float y3 = Ar[id.w & (GD - 1)] + base;
      sum += y0 + y1 + y2 + y3;
      ssq += y0 * y0 + y1 * y1 + y2 * y2 + y3 * y3;
    }
  }
  __shared__ float rs[256], rq[256];
  rs[tid] = sum; rq[tid] = ssq;
  __syncthreads();
  for (int t = 128; t > 0; t >>= 1) {
    if (tid < t) { rs[tid] += rs[tid + t]; rq[tid] += rq[tid + t]; }
    __syncthreads();
  }
  if (tid == 0) {
    int key = ((b * 4 + grp) * 8 + s) * 2;
    part[key] = rs[0]; part[key + 1] = rq[0];
  }
}

__global__ void k_statsfin(const float* __restrict__ part, float* __restrict__ fin, float invN) {
  int t = threadIdx.x;  // 64 = 16 b * 4 groups
  float s = 0.f, q = 0.f;
  for (int i = 0; i < 8; i++) { s += part[(t * 8 + i) * 2]; q += part[(t * 8 + i) * 2 + 1]; }
  float mean = s * invN;
  float var = q * invN - mean * mean;
  float rstd = 1.0f / sqrtf(fmaxf(var, 0.0f) + EPS_);  // guard: never NaN
  fin[t * 2] = mean; fin[t * 2 + 1] = rstd;
}

// ---------------- h = max_k leaky(GN(y)); write transposed hT[b][g][o] (bf16) ----------------
__global__ void k_h(const ushort* __restrict__ A, const float* __restrict__ Bq,
                    const int* __restrict__ idx1, const float* __restrict__ fin,
                    const float* __restrict__ gam, const float* __restrict__ bet,
                    ushort* __restrict__ hT) {
  __shared__ ushort tile[64][66];  // pitch 66: conflict-free column reads
  int g0 = blockIdx.x * 64, o0 = blockIdx.y * 64, b = blockIdx.z;
  int tid = threadIdx.x;
  int gx = tid & 63, oy = tid >> 6;
  int g = g0 + gx;
  int4 id = *reinterpret_cast<const int4*>(&idx1[((size_t)b * GD + g) * 4]);
  id.x &= (GS - 1); id.y &= (GS - 1); id.z &= (GS - 1); id.w &= (GS - 1);
#pragma unroll
  for (int oi = 0; oi < 16; oi++) {
    int ol = oi * 4 + oy;
    int o = o0 + ol;
    const ushort* Ar = A + ((size_t)b * M1 + o) * GS;
    float base = Bq[((size_t)b * M1 + o) * GD + g];
    float mean = fin[(b * 4 + (o >> 7)) * 2];
    float rstd = fin[(b * 4 + (o >> 7)) * 2 + 1];
    float ga = gam[o], be = bet[o];
    float m = -1e30f;
    {
      float y = bf2f(Ar[id.x]) + base; float v = (y - mean) * rstd * ga + be;
      v = v >= 0.f ? v : NEG * v; m = fmaxf(m, v);
    }
    {
      float y = bf2f(Ar[id.y]) + base; float v = (y - mean) * rstd * ga + be;
      v = v >= 0.f ? v : NEG * v; m = fmaxf(m, v);
    }
    {
      float y = bf2f(Ar[id.z]) + base; float v = (y - mean) * rstd * ga + be;
      v = v >= 0.f ? v : NEG * v; m = fmaxf(m, v);
    }
    {
      float y = bf2f(Ar[id.w]) + base; float v = (y - mean) * rstd * ga + be;
      v = v >= 0.f ? v : NEG * v; m = fmaxf(m, v);
    }
    tile[ol][gx] = f2bf(m);
  }
  __syncthreads();
  int col = tid & 63, r4 = tid >> 6;
#pragma unroll
  for (int i = 0; i < 16; i++) {
    int gl = i * 4 + r4;
    hT[((size_t)b * GD + g0 + gl) * K2C + o0 + col] = tile[col][gl];
  }
}

// ---------------- final: out[b][o][g] = max_k leaky(GN2(A2[gather]+B2q)) -> f32 ----------------
__global__ void k_out(const float* __restrict__ A2, const float* __restrict__ B2q,
                      const int* __restrict__ idx2, const float* __restrict__ fin,
                      const float* __restrict__ gam, const float* __restrict__ bet,
                      float* __restrict__ out) {
  int b = blockIdx.z, o = blockIdx.y;
  int g = blockIdx.x * 256 + threadIdx.x;
  const float* Ar = A2 + ((size_t)b * M2 + o) * GD;
  float base = B2q[((size_t)b * M2 + o) * GD + g];
  int4 id = *reinterpret_cast<const int4*>(&idx2[((size_t)b * GD + g) * 4]);
  id.x &= (GD - 1); id.y &= (GD - 1); id.z &= (GD - 1); id.w &= (GD - 1);
  float mean = fin[(b * 4 + o / 96) * 2];
  float rstd = fin[(b * 4 + o / 96) * 2 + 1];
  float ga = gam[o], be = bet[o];
  float m = -1e30f;
  { float y = Ar[id.x] + base; float v = (y - mean) * rstd * ga + be; v = v >= 0.f ? v : NEG * v; m = fmaxf(m, v); }
  { float y = Ar[id.y] + base; float v = (y - mean) * rstd * ga + be; v = v >= 0.f ? v : NEG * v; m = fmaxf(m, v); }
  { float y = Ar[id.z] + base; float v = (y - mean) * rstd * ga + be; v = v >= 0.f ? v : NEG * v; m = fmaxf(m, v); }
  { float y = Ar[id.w] + base; float v = (y - mean) * rstd * ga + be; v = v >= 0.f ? v : NEG * v; m = fmaxf(m, v); }
  out[((size_t)b * M2 + o) * GD + g] = m;
}

extern "C" void kernel_launch(void* const* d_in, const int* in_sizes, int n_in,
                              void* d_out, int out_size, void* d_ws, size_t ws_size,
                              hipStream_t stream) {
  (void)in_sizes; (void)n_in; (void)out_size;
  const float* coor  = (const float*)d_in[0];  // [16][3][4096] f32
  const float* f     = (const float*)d_in[1];  // [16][384][4096]
  const float* coorq = (const float*)d_in[2];  // [16][3][1024]
  const float* fq    = (const float*)d_in[3];  // [16][384][1024]
  const float* W1    = (const float*)d_in[4];  // [512][768]
  const float* g1    = (const float*)d_in[5];
  const float* b1    = (const float*)d_in[6];
  const float* W2    = (const float*)d_in[7];  // [384][1024]
  const float* g2    = (const float*)d_in[8];
  const float* b2    = (const float*)d_in[9];

  // Required workspace ~182.5 MB (internal buffers unchanged; skip cleanly if short).
  if (ws_size < 182468608u) return;

  char* ws = (char*)d_ws;
  int*    idx1 = (int*)(ws + 0);            // 256 KB
  int*    idx2 = (int*)(ws + 0x40000);      // 256 KB
  float*  s1p  = (float*)(ws + 0x80000);    // 4 KB
  float*  s1f  = (float*)(ws + 0x81000);
  float*  s2p  = (float*)(ws + 0x82000);
  float*  s2f  = (float*)(ws + 0x83000);
  ushort* W1a  = (ushort*)(ws + 0x84000);           // 512*384 bf16
  ushort* W1d  = W1a + (size_t)512 * 384;
  ushort* W2a  = W1d + (size_t)512 * 384;           // 384*512
  ushort* W2d  = W2a + (size_t)384 * 512;
  ushort* fT   = W2d + (size_t)384 * 512;           // [16][4096][384] bf16, 50.33 MB
  ushort* fqT  = fT + (size_t)B_ * GS * CIN;        // [16][1024][384] bf16, 12.6 MB
  ushort* Abuf = fqT + (size_t)B_ * GD * CIN;       // [16][512][4096] bf16, 67.1 MB
  float*  Bq   = (float*)(Abuf + (size_t)B_ * M1 * GS);   // [16][512][1024] f32, 33.6 MB
  ushort* hT   = (ushort*)((char*)Bq + (size_t)B_ * M1 * GD * 4); // [16][1024][512] bf16, 16.8 MB
  float*  A2   = (float*)fT;                        // [16][384][1024] f32 (aliases dead fT)
  float*  B2q  = A2 + (size_t)B_ * M2 * GD;         // [16][384][1024] f32

  // 1. transposes (+f32->bf16 convert) + weight prep
  k_transpose<<<dim3(GS / 32, CIN / 32, B_), dim3(32, 8), 0, stream>>>(f, fT, CIN, GS);
  k_transpose<<<dim3(GD / 32, CIN / 32, B_), dim3(32, 8), 0, stream>>>(fq, fqT, CIN, GD);
  k_wprep<<<dim3(512 * 384 / 256), 256, 0, stream>>>(W1, W1a, W1d, 384);
  k_wprep<<<dim3(384 * 512 / 256), 256, 0, stream>>>(W2, W2a, W2d, 512);

  // 2. kNN index sets (wave-per-query, branchless; both depend only on coords)
  k_knn<GS><<<dim3(GD / 4, B_), 256, 0, stream>>>(coorq, coor, idx1);
  k_knn<GD><<<dim3(GD / 4, B_), 256, 0, stream>>>(coorq, coorq, idx2);

  // 3. block1 GEMMs: A = W1a*f (bf16 out), Bq = W1d*fq (f32 out)
  k_gemm<true ><<<dim3(GS / 128, M1 / 128, B_), 256, 0, stream>>>(W1a, fT, Abuf, M1, CIN, GS);
  k_gemm<false><<<dim3(GD / 128, M1 / 128, B_), 256, 0, stream>>>(W1d, fqT, Bq, M1, CIN, GD);

  // 4. GN1 stats + h (writes hT transposed for GEMM2)
  k_stats1<<<dim3(8, 4, B_), 256, 0, stream>>>(Abuf, Bq, idx1, s1p);
  k_statsfin<<<1, 64, 0, stream>>>(s1p, s1f, 1.0f / 524288.0f);
  k_h<<<dim3(GD / 64, M1 / 64, B_), 256, 0, stream>>>(Abuf, Bq, idx1, s1f, g1, b1, hT);

  // 5. block2 GEMMs (outputs alias dead fT region)
  k_gemm<false><<<dim3(GD / 128, M2 / 128, B_), 256, 0, stream>>>(W2a, hT, A2, M2, K2C, GD);
  k_gemm<false><<<dim3(GD / 128, M2 / 128, B_), 256, 0, stream>>>(W2d, hT, B2q, M2, K2C, GD);

  // 6. GN2 stats + final output (f32)
  k_stats2<<<dim3(8, 4, B_), 256, 0, stream>>>(A2, B2q, idx2, s2p);
  k_statsfin<<<1, 64, 0, stream>>>(s2p, s2f, 1.0f / 393216.0f);
  k_out<<<dim3(GD / 256, M2, B_), 256, 0, stream>>>(A2, B2q, idx2, s2f, g2, b2, (float*)d_out);
}